// Round 4
// baseline (633.876 us; speedup 1.0000x reference)
//
#include <hip/hip_runtime.h>
#include <hip/hip_cooperative_groups.h>
namespace cg = cooperative_groups;

#define HDIM 1024
#define H4   4096
#define VD   32000
#define WINN 129
#define NEGV (-1e30f)

// ws float offsets
#define X_    0        // 1024: h of current layer / fc1 output
#define G_    2048     // 4096: lstm gates
#define ATT1_ 6144     // 512
#define CAT_  8192     // 2048: [ctx | h_t]
#define A_    10240    // 129: raw scores
#define SC_   10376    // p, off
#define IW_   10380    // int: ws_i, we_i
#define PM_   10496    // 2048 partial max
#define PS_   12544    // 2048 partial sumexp
#define LOG_  16384    // 32000 logits

// d_out float element offsets
#define O_Y   0
#define O_OUT 32000
#define O_HN  33024
#define O_CN  35072
#define O_A   37120

__device__ __forceinline__ float wred(float v){
  #pragma unroll
  for(int off=32; off; off>>=1) v += __shfl_xor(v, off, 64);
  return v;
}
__device__ __forceinline__ float wmax(float v){
  #pragma unroll
  for(int off=32; off; off>>=1) v = fmaxf(v, __shfl_xor(v, off, 64));
  return v;
}
__device__ __forceinline__ float sigf(float x){ return 1.f/(1.f+expf(-x)); }
__device__ __forceinline__ float dot4(float4 a, float4 b){
  return a.x*b.x + a.y*b.y + a.z*b.z + a.w*b.w;
}

__global__ __launch_bounds__(512) void k_all(
    const int* __restrict__ slen, const float* __restrict__ enc,
    const int* __restrict__ word, const float* __restrict__ h0,
    const float* __restrict__ c0, const float* __restrict__ emb,
    const float* __restrict__ wih, const float* __restrict__ whh,
    const float* __restrict__ bih, const float* __restrict__ bhh,
    const float* __restrict__ a1w, const float* __restrict__ a1b,
    const float* __restrict__ a2w, const float* __restrict__ a2b,
    const float* __restrict__ f1w, const float* __restrict__ f1b,
    const float* __restrict__ f2w, const float* __restrict__ f2b,
    float* __restrict__ ws, float* __restrict__ out)
{
  cg::grid_group grid = cg::this_grid();
  const int t    = threadIdx.x;
  const int gt   = blockIdx.x*512 + t;
  const int w    = gt >> 6;          // global wave id 0..2047
  const int lane = t & 63;

  // ---- stage 1: LSTM layer 0 gates (4096 rows, 2 per wave)
  {
    const float* xp = emb + ((size_t)word[0]<<10);
    float4 xv[4], hv[4];
    #pragma unroll
    for (int j=0;j<4;j++){ int o = lane*4+256*j; xv[j] = *(const float4*)(xp+o); hv[j] = *(const float4*)(h0+o); }
    #pragma unroll
    for (int rr=0; rr<2; rr++){
      int r = w + rr*2048;
      const float* wi = wih + ((size_t)r<<10);
      const float* wh = whh + ((size_t)r<<10);
      float acc = 0.f;
      #pragma unroll
      for (int j=0;j<4;j++){
        int o = lane*4+256*j;
        acc += dot4(*(const float4*)(wi+o), xv[j]);
        acc += dot4(*(const float4*)(wh+o), hv[j]);
      }
      acc = wred(acc);
      if (lane==0) ws[G_+r] = acc + bih[r] + bhh[r];
    }
  }
  grid.sync();
  // ---- stage 2: act 0
  if (gt < 1024){
    float gi = ws[G_+gt], gf = ws[G_+1024+gt], gg = ws[G_+2048+gt], go = ws[G_+3072+gt];
    float c = sigf(gf)*c0[gt] + sigf(gi)*tanhf(gg);
    float h = sigf(go)*tanhf(c);
    ws[X_+gt] = h;
    out[O_HN+gt] = h; out[O_CN+gt] = c;
  }
  grid.sync();
  // ---- stage 3: LSTM layer 1 gates
  {
    const float* hin = h0 + HDIM;
    float4 xv[4], hv[4];
    #pragma unroll
    for (int j=0;j<4;j++){ int o = lane*4+256*j; xv[j] = *(const float4*)(ws+X_+o); hv[j] = *(const float4*)(hin+o); }
    #pragma unroll
    for (int rr=0; rr<2; rr++){
      int r = w + rr*2048;
      const float* wi = wih + (size_t)H4*HDIM + ((size_t)r<<10);
      const float* wh = whh + (size_t)H4*HDIM + ((size_t)r<<10);
      float acc = 0.f;
      #pragma unroll
      for (int j=0;j<4;j++){
        int o = lane*4+256*j;
        acc += dot4(*(const float4*)(wi+o), xv[j]);
        acc += dot4(*(const float4*)(wh+o), hv[j]);
      }
      acc = wred(acc);
      if (lane==0) ws[G_+r] = acc + bih[H4+r] + bhh[H4+r];
    }
  }
  grid.sync();
  // ---- stage 4: act 1
  if (gt < 1024){
    float gi = ws[G_+gt], gf = ws[G_+1024+gt], gg = ws[G_+2048+gt], go = ws[G_+3072+gt];
    float c = sigf(gf)*c0[HDIM+gt] + sigf(gi)*tanhf(gg);
    float h = sigf(go)*tanhf(c);
    ws[X_+gt] = h;
    ws[CAT_+HDIM+gt] = h;
    out[O_HN+HDIM+gt] = h; out[O_CN+HDIM+gt] = c;
  }
  grid.sync();
  // ---- stage 5: att fc1 (512 rows)
  if (w < 512){
    const float* wr = a1w + ((size_t)w<<10);
    float acc = 0.f;
    #pragma unroll
    for (int j=0;j<4;j++){
      int o = lane*4+256*j;
      acc += dot4(*(const float4*)(wr+o), *(const float4*)(ws+X_+o));
    }
    acc = wred(acc);
    if (lane==0) ws[ATT1_+w] = tanhf(acc + a1b[w]);
  }
  grid.sync();
  // ---- stage 6: p (redundant per active wave) + 129 score rows
  if (w < WINN){
    float pacc = 0.f;
    #pragma unroll
    for (int j=0;j<2;j++){
      int o = lane*4+256*j;
      pacc += dot4(*(const float4*)(a2w+o), *(const float4*)(ws+ATT1_+o));
    }
    pacc = wred(pacc);
    float Sf = (float)slen[0];
    float p  = Sf * sigf(pacc + a2b[0]);
    int wsi = (int)rintf(fmaxf(p - 64.f, 0.f));
    int wei = (int)rintf(fminf(p + 64.f, Sf - 1.f));
    if (w==0 && lane==0){
      ws[SC_] = p;
      ((int*)ws)[IW_] = wsi; ((int*)ws)[IW_+1] = wei;
    }
    int idx = wsi + w;
    int smax = slen[0]-1;
    int ci = idx > smax ? smax : (idx < 0 ? 0 : idx);
    const float* er = enc + ((size_t)ci<<10);
    float acc = 0.f;
    #pragma unroll
    for (int j=0;j<4;j++){
      int o = lane*4+256*j;
      acc += dot4(*(const float4*)(er+o), *(const float4*)(ws+X_+o));
    }
    acc = wred(acc);
    if (lane==0) ws[A_+w] = (idx <= wei) ? acc : NEGV;
  }
  grid.sync();
  // ---- stage 7: softmax (redundant per block) + ctx (4 elems/block) + a out
  {
    __shared__ float sarr[WINN];
    __shared__ float av[WINN];
    __shared__ int   cis[WINN];
    __shared__ float red2[2];
    float p = ws[SC_];
    int wsi = ((int*)ws)[IW_], wei = ((int*)ws)[IW_+1];
    int smax = slen[0]-1;
    if (t < WINN){
      sarr[t] = ws[A_+t];
      int idx = wsi + t;
      cis[t] = idx > smax ? smax : (idx < 0 ? 0 : idx);
    }
    __syncthreads();
    if (t < 64){
      float m = fmaxf(sarr[t], sarr[t+64]);
      if (t==0) m = fmaxf(m, sarr[128]);
      m = wmax(m);
      if (t==0) red2[0] = m;
    }
    __syncthreads();
    float M = red2[0];
    if (t < 64){
      float e = expf(sarr[t]-M) + expf(sarr[t+64]-M);
      if (t==0) e += expf(sarr[128]-M);
      e = wred(e);
      if (t==0) red2[1] = e;
    }
    __syncthreads();
    float sm = red2[1];
    if (t < WINN){
      int idx = wsi + t;
      float a = expf(sarr[t]-M) / sm;
      a = (idx <= wei) ? a * expf(((float)idx - p) * (1.f/2048.f)) : 0.f;
      av[t] = a;
      if (blockIdx.x==0) out[O_A+t] = a;
    }
    __syncthreads();
    int v = t >> 6;                       // wave in block, 0..7
    if (v < 4){
      int i = blockIdx.x*4 + v;           // 0..1023
      float acc = av[lane]      * enc[((size_t)cis[lane]<<10) + i]
                + av[lane+64]   * enc[((size_t)cis[lane+64]<<10) + i];
      if (lane==0) acc += av[128] * enc[((size_t)cis[128]<<10) + i];
      acc = wred(acc);
      if (lane==0) ws[CAT_+i] = acc;
    }
  }
  grid.sync();
  // ---- stage 8: fc1 (1024 rows)
  if (w < 1024){
    const float* wr = f1w + ((size_t)w<<11);
    float acc = 0.f;
    #pragma unroll
    for (int j=0;j<8;j++){
      int o = lane*4+256*j;
      acc += dot4(*(const float4*)(wr+o), *(const float4*)(ws+CAT_+o));
    }
    acc = wred(acc);
    if (lane==0){
      float o = tanhf(acc + f1b[w]);
      ws[X_+w] = o;
      out[O_OUT+w] = o;
    }
  }
  grid.sync();
  // ---- stage 9: fc2 (32000 rows, ~16/wave) with fused online LSE partials
  {
    float4 xv[4];
    #pragma unroll
    for (int j=0;j<4;j++){ int o = lane*4+256*j; xv[j] = *(const float4*)(ws+X_+o); }
    float mw = -INFINITY, sw = 0.f;
    #pragma unroll 4
    for (int j=0;j<16;j++){
      int r = w + 2048*j;
      if (r < VD){
        const float* wr = f2w + ((size_t)r<<10);
        float acc = 0.f;
        #pragma unroll
        for (int jj=0;jj<4;jj++){
          int o = lane*4+256*jj;
          acc += dot4(*(const float4*)(wr+o), xv[jj]);
        }
        acc = wred(acc);
        float v = acc + f2b[r];
        if (lane==0) ws[LOG_+r] = v;
        float mn = fmaxf(mw, v);
        sw = sw*expf(mw-mn) + expf(v-mn);
        mw = mn;
      }
    }
    if (lane==0){ ws[PM_+w] = mw; ws[PS_+w] = sw; }
  }
  grid.sync();
  // ---- stage 10: reduce 2048 LSE partials in block 0
  if (blockIdx.x==0){
    __shared__ float pm[8], ps[8];
    float m = -INFINITY, s = 0.f;
    for (int k=t; k<2048; k+=512){
      float mk = ws[PM_+k], sk = ws[PS_+k];
      float mn = fmaxf(m, mk);
      s = s*expf(m-mn) + sk*expf(mk-mn);
      m = mn;
    }
    #pragma unroll
    for (int off=32; off; off>>=1){
      float mo = __shfl_xor(m, off, 64), so = __shfl_xor(s, off, 64);
      float mn = fmaxf(m, mo);
      s = s*expf(m-mn) + so*expf(mo-mn);
      m = mn;
    }
    if (lane==0){ pm[t>>6] = m; ps[t>>6] = s; }
    __syncthreads();
    if (t==0){
      float M = pm[0], S = ps[0];
      for (int k=1;k<8;k++){
        float mn = fmaxf(M, pm[k]);
        S = S*expf(M-mn) + ps[k]*expf(pm[k]-mn);
        M = mn;
      }
      ws[SC_+1] = M + logf(S);
    }
  }
  grid.sync();
  // ---- stage 11: y = log - off
  {
    float off = ws[SC_+1];
    if (gt < 8000){
      float4 v = *(const float4*)(ws + LOG_ + gt*4);
      v.x -= off; v.y -= off; v.z -= off; v.w -= off;
      *(float4*)(out + O_Y + gt*4) = v;
    }
  }
}

extern "C" void kernel_launch(void* const* d_in, const int* in_sizes, int n_in,
                              void* d_out, int out_size, void* d_ws, size_t ws_size,
                              hipStream_t stream) {
  const int*   slen = (const int*)d_in[0];
  const float* enc  = (const float*)d_in[1];
  const int*   word = (const int*)d_in[2];
  const float* h0   = (const float*)d_in[3];
  const float* c0   = (const float*)d_in[4];
  const float* emb  = (const float*)d_in[5];
  const float* wih  = (const float*)d_in[6];
  const float* whh  = (const float*)d_in[7];
  const float* bih  = (const float*)d_in[8];
  const float* bhh  = (const float*)d_in[9];
  const float* a1w  = (const float*)d_in[10];
  const float* a1b  = (const float*)d_in[11];
  const float* a2w  = (const float*)d_in[12];
  const float* a2b  = (const float*)d_in[13];
  const float* f1w  = (const float*)d_in[14];
  const float* f1b  = (const float*)d_in[15];
  const float* f2w  = (const float*)d_in[16];
  const float* f2b  = (const float*)d_in[17];
  float* ws  = (float*)d_ws;
  float* out = (float*)d_out;

  void* args[] = { (void*)&slen, (void*)&enc, (void*)&word, (void*)&h0, (void*)&c0,
                   (void*)&emb, (void*)&wih, (void*)&whh, (void*)&bih, (void*)&bhh,
                   (void*)&a1w, (void*)&a1b, (void*)&a2w, (void*)&a2b,
                   (void*)&f1w, (void*)&f1b, (void*)&f2w, (void*)&f2b,
                   (void*)&ws, (void*)&out };
  hipLaunchCooperativeKernel((void*)k_all, dim3(256), dim3(512), args, 0, stream);
}